// Round 4
// baseline (196.094 us; speedup 1.0000x reference)
//
#include <hip/hip_runtime.h>

// LJ pair-energy sum, round 4: MLP experiment.
// 8 pairs/thread; all 16 position gathers issued before any math so each
// wave has 16 outstanding divergent dwordx4 gathers (vs 8 interleaved).
// Discriminates latency-bound (win) vs L2-request-throughput-bound (flat).

typedef int vint4 __attribute__((ext_vector_type(4)));

__global__ __launch_bounds__(256) void repack_kernel(
    const float* __restrict__ x, float* __restrict__ xp, int n3)
{
    int t = blockIdx.x * 256 + threadIdx.x;
    if (t < n3) {
        float v = x[t];
        int p = t / 3;
        int c = t - 3 * p;
        xp[4 * p + c] = v;       // .w never read
    }
}

__global__ __launch_bounds__(256) void lj_pairs8_kernel(
    const float4* __restrict__ xp,
    const float* __restrict__ eps_p,
    const float* __restrict__ sig_p,
    const float* __restrict__ box_p,
    const vint4* __restrict__ idx_i4,
    const vint4* __restrict__ idx_j4,
    double*      __restrict__ partial)
{
    const int t = blockIdx.x * blockDim.x + threadIdx.x;

    const float eps  = eps_p[0];
    const float sig  = sig_p[0];
    const float sig2 = sig * sig;
    const float L0 = box_p[0], L1 = box_p[1], L2 = box_p[2];
    const float i0 = 1.0f / L0, i1 = 1.0f / L1, i2 = 1.0f / L2;

    // 8 pairs: two nt int4 loads per index stream (stream-once, keep L2 clean)
    const vint4 iiA = __builtin_nontemporal_load(idx_i4 + 2 * t);
    const vint4 iiB = __builtin_nontemporal_load(idx_i4 + 2 * t + 1);
    const vint4 jjA = __builtin_nontemporal_load(idx_j4 + 2 * t);
    const vint4 jjB = __builtin_nontemporal_load(idx_j4 + 2 * t + 1);
    const int ia[8] = {iiA.x, iiA.y, iiA.z, iiA.w, iiB.x, iiB.y, iiB.z, iiB.w};
    const int ja[8] = {jjA.x, jjA.y, jjA.z, jjA.w, jjB.x, jjB.y, jjB.z, jjB.w};

    // Phase 1: issue ALL gathers (16 outstanding dwordx4 per thread)
    float4 pi[8], pj[8];
#pragma unroll
    for (int k = 0; k < 8; ++k) pi[k] = xp[ia[k]];
#pragma unroll
    for (int k = 0; k < 8; ++k) pj[k] = xp[ja[k]];

    // Phase 2: math
    float sum = 0.0f;
#pragma unroll
    for (int k = 0; k < 8; ++k) {
        float dx = pi[k].x - pj[k].x;
        float dy = pi[k].y - pj[k].y;
        float dz = pi[k].z - pj[k].z;
        // jnp.round == round-half-even == rintf (RNE)
        dx -= L0 * rintf(dx * i0);
        dy -= L1 * rintf(dy * i1);
        dz -= L2 * rintf(dz * i2);
        const float r2 = dx * dx + dy * dy + dz * dz;
        const float s2 = sig2 / r2;
        const float s6 = s2 * s2 * s2;
        sum += s6 * s6 - s6;
    }
    double dsum = (double)(4.0f * eps * sum);

    #pragma unroll
    for (int off = 32; off > 0; off >>= 1)
        dsum += __shfl_down(dsum, off, 64);

    __shared__ double wsum[4];
    if ((threadIdx.x & 63) == 0) wsum[threadIdx.x >> 6] = dsum;
    __syncthreads();
    if (threadIdx.x == 0)
        partial[blockIdx.x] = wsum[0] + wsum[1] + wsum[2] + wsum[3];
}

__global__ __launch_bounds__(256) void reduce_kernel(
    const double* __restrict__ partial, int n, float* __restrict__ out)
{
    double s = 0.0;
    for (int i = threadIdx.x; i < n; i += 256)
        s += partial[i];
    #pragma unroll
    for (int off = 32; off > 0; off >>= 1)
        s += __shfl_down(s, off, 64);
    __shared__ double wsum[4];
    if ((threadIdx.x & 63) == 0) wsum[threadIdx.x >> 6] = s;
    __syncthreads();
    if (threadIdx.x == 0)
        out[0] = (float)(wsum[0] + wsum[1] + wsum[2] + wsum[3]);
}

extern "C" void kernel_launch(void* const* d_in, const int* in_sizes, int n_in,
                              void* d_out, int out_size, void* d_ws, size_t ws_size,
                              hipStream_t stream) {
    const float* x     = (const float*)d_in[0];
    const float* eps   = (const float*)d_in[1];
    const float* sigma = (const float*)d_in[2];
    const float* box   = (const float*)d_in[3];
    const vint4* ii    = (const vint4*)d_in[4];
    const vint4* jj    = (const vint4*)d_in[5];
    float* out = (float*)d_out;

    const int n_pairs = in_sizes[4];            // 8388608
    const int n_part  = in_sizes[0] / 3;        // 262144
    const int block = 256;
    const int grid = (n_pairs / 8) / block;     // 4096 blocks (8 pairs/thread)

    const size_t packed_bytes = (size_t)n_part * 16;            // 4 MB
    float4* xp = (float4*)d_ws;
    double* partial = (double*)((char*)d_ws + packed_bytes);

    const int n3 = n_part * 3;
    repack_kernel<<<(n3 + block - 1) / block, block, 0, stream>>>(x, (float*)xp, n3);
    lj_pairs8_kernel<<<grid, block, 0, stream>>>(xp, eps, sigma, box, ii, jj, partial);
    reduce_kernel<<<1, block, 0, stream>>>(partial, grid, out);
}